// Round 4
// baseline (521.207 us; speedup 1.0000x reference)
//
#include <hip/hip_runtime.h>
#include <math.h>

// Router: logits = hidden[16384,4096] @ W[64,4096]^T + b; top-2 + softmax.
// Output (f32, concat): logits[nrows*64] | indices[nrows*2] | weights[nrows*2]
//
// MFMA with EXACT 3-way bf16 split (x = xh+xm+xl), 6 products -> f32-grade
// logits. Partition: 16 rows/block, K split across 4 waves, 1024 blocks.
// NEW (round 4): runtime layout PROBE - one MFMA with A=identity,
// B=position-code tells each lane which (m,n) its accumulator regs hold,
// making the epilogue correct under ANY hardware fragment layout convention
// (C/D row/col order, operand roles, k-permutations all self-calibrate).

namespace {

constexpr int Hdim  = 4096;
constexpr int Edim  = 64;
constexpr int RPB   = 16;          // rows per block
constexpr int KW    = Hdim / 4;    // k-range per wave
constexpr int PLANE = Edim * Hdim; // elements per W bf16 plane

typedef __attribute__((ext_vector_type(4))) float f32x4;
typedef __attribute__((ext_vector_type(8))) short bf16x8;

// Exact 3-way split: x == h + m + l (bf16 planes; 8+8+8 >= f32's 24 mantissa bits).
__device__ __forceinline__ void split3(float x, unsigned& h, unsigned& m, unsigned& l) {
    unsigned uh = __float_as_uint(x);
    h = uh >> 16;
    float r1 = x - __uint_as_float(uh & 0xFFFF0000u);
    unsigned um = __float_as_uint(r1);
    m = um >> 16;
    float r2 = r1 - __uint_as_float(um & 0xFFFF0000u);
    l = __float_as_uint(r2) >> 16;
}

// f32 -> bf16 by truncation (exact for the probe's small integers and 1.0)
__device__ __forceinline__ short ftob(float x) {
    return (short)(__float_as_uint(x) >> 16);
}

__global__ __launch_bounds__(256)
void convert_w3(const float* __restrict__ W, unsigned short* __restrict__ wsp) {
    const int i = blockIdx.x * 256 + threadIdx.x;   // over Edim*Hdim
    unsigned h, m, l;
    split3(W[i], h, m, l);
    wsp[i]             = (unsigned short)h;
    wsp[PLANE + i]     = (unsigned short)m;
    wsp[2 * PLANE + i] = (unsigned short)l;
}

template <bool PRE>
__global__ __launch_bounds__(256)
void router_mfma(const float* __restrict__ hid,
                 const void* __restrict__ Wsrc,
                 const float* __restrict__ bias,
                 float* __restrict__ out, int nrows)
{
    __shared__ float red[4][RPB][Edim + 4];   // 17408 B, K-partial reduction
    __shared__ float fin[RPB][Edim + 1];      //  4160 B, final logits

    const int tid  = threadIdx.x;
    const int wave = tid >> 6;
    const int lane = tid & 63;
    const int l15  = lane & 15;
    const int lk   = lane >> 4;
    const int rowBase = blockIdx.x * RPB;
    const int k0 = wave * KW + lk * 8;

    // ---- layout probe: D[m][n] = m*16+n under MY loading convention ----
    // A[m][k] = (k==m); B[k][n] = k*16+n (k<16). All values exact in bf16.
    bf16x8 aid, benc;
    #pragma unroll
    for (int e = 0; e < 8; ++e) {
        const int kl = lk * 8 + e;
        aid[e]  = ftob(kl == l15 ? 1.0f : 0.0f);
        benc[e] = ftob(kl < 16 ? (float)(kl * 16 + l15) : 0.0f);
    }
    f32x4 pr = (f32x4){0.f, 0.f, 0.f, 0.f};
    pr = __builtin_amdgcn_mfma_f32_16x16x32_bf16(aid, benc, pr, 0, 0, 0);
    int prow[4], pcol[4];
    #pragma unroll
    for (int r = 0; r < 4; ++r) {
        const int code = (int)pr[r];
        prow[r] = (code >> 4) & 15;
        pcol[r] = code & 15;
    }

    const float* aptr = hid + (size_t)(rowBase + l15) * Hdim + k0;

    f32x4 acc[4];
    #pragma unroll
    for (int t = 0; t < 4; ++t) acc[t] = (f32x4){0.f, 0.f, 0.f, 0.f};

    for (int s = 0; s < KW / 32; ++s) {
        // A fragments: exact 3-way split of 8 consecutive f32
        f32x4 a0 = *(const f32x4*)(aptr);
        f32x4 a1 = *(const f32x4*)(aptr + 4);
        aptr += 32;
        bf16x8 ah, am, al;
        #pragma unroll
        for (int j = 0; j < 4; ++j) {
            unsigned h, m, l;
            split3(a0[j], h, m, l);
            ah[j] = (short)h;  am[j] = (short)m;  al[j] = (short)l;
            split3(a1[j], h, m, l);
            ah[4 + j] = (short)h;  am[4 + j] = (short)m;  al[4 + j] = (short)l;
        }

        #pragma unroll
        for (int t = 0; t < 4; ++t) {
            bf16x8 bh, bm, bl;
            if (PRE) {
                const unsigned short* wsp = (const unsigned short*)Wsrc;
                const size_t boff = (size_t)(l15 + 16 * t) * Hdim + k0 + s * 32;
                bh = *(const bf16x8*)(wsp + boff);
                bm = *(const bf16x8*)(wsp + PLANE + boff);
                bl = *(const bf16x8*)(wsp + 2 * PLANE + boff);
            } else {
                const float* wf = (const float*)Wsrc
                                + (size_t)(l15 + 16 * t) * Hdim + k0 + s * 32;
                f32x4 b0 = *(const f32x4*)(wf);
                f32x4 b1 = *(const f32x4*)(wf + 4);
                #pragma unroll
                for (int j = 0; j < 4; ++j) {
                    unsigned h, m, l;
                    split3(b0[j], h, m, l);
                    bh[j] = (short)h;  bm[j] = (short)m;  bl[j] = (short)l;
                    split3(b1[j], h, m, l);
                    bh[4 + j] = (short)h;  bm[4 + j] = (short)m;  bl[4 + j] = (short)l;
                }
            }
            // (ah+am+al)(bh+bm+bl) minus terms < 2^-24 relative
            acc[t] = __builtin_amdgcn_mfma_f32_16x16x32_bf16(al, bh, acc[t], 0, 0, 0);
            acc[t] = __builtin_amdgcn_mfma_f32_16x16x32_bf16(am, bm, acc[t], 0, 0, 0);
            acc[t] = __builtin_amdgcn_mfma_f32_16x16x32_bf16(ah, bl, acc[t], 0, 0, 0);
            acc[t] = __builtin_amdgcn_mfma_f32_16x16x32_bf16(am, bh, acc[t], 0, 0, 0);
            acc[t] = __builtin_amdgcn_mfma_f32_16x16x32_bf16(ah, bm, acc[t], 0, 0, 0);
            acc[t] = __builtin_amdgcn_mfma_f32_16x16x32_bf16(ah, bh, acc[t], 0, 0, 0);
        }
    }

    // ---- partial-K reduction via LDS, placement from the PROBE ----
    #pragma unroll
    for (int t = 0; t < 4; ++t)
        #pragma unroll
        for (int r = 0; r < 4; ++r)
            red[wave][prow[r]][t * 16 + pcol[r]] = acc[t][r];

    __syncthreads();

    #pragma unroll
    for (int j = 0; j < 4; ++j) {
        const int e   = tid + j * 256;        // 0..1023 over 16x64
        const int row = e >> 6;
        const int col = e & 63;
        float v = red[0][row][col] + red[1][row][col]
                + red[2][row][col] + red[3][row][col] + bias[col];
        out[(size_t)(rowBase + row) * Edim + col] = v;
        fin[row][col] = v;
    }
    __syncthreads();

    // ---- top-2 + softmax: one thread per row ----
    if (tid < RPB) {
        const float* lr = &fin[tid][0];
        float m1 = lr[0]; int i1 = 0;
        #pragma unroll 8
        for (int e2 = 1; e2 < Edim; ++e2) {
            float v = lr[e2];
            if (v > m1) { m1 = v; i1 = e2; }
        }
        float m2 = -INFINITY; int i2 = 0;
        #pragma unroll 8
        for (int e2 = 0; e2 < Edim; ++e2) {
            if (e2 == i1) continue;
            float v = lr[e2];
            if (v > m2) { m2 = v; i2 = e2; }
        }
        const float t  = expf(m2 - m1);
        const float w1 = 1.0f / (1.0f + t);
        const float w2 = t * w1;

        const size_t ro    = (size_t)(rowBase + tid);
        const size_t base2 = (size_t)nrows * Edim;
        const size_t base3 = base2 + (size_t)nrows * 2;
        out[base2 + ro * 2 + 0] = (float)i1;
        out[base2 + ro * 2 + 1] = (float)i2;
        out[base3 + ro * 2 + 0] = w1;
        out[base3 + ro * 2 + 1] = w2;
    }
}

}  // namespace

extern "C" void kernel_launch(void* const* d_in, const int* in_sizes, int n_in,
                              void* d_out, int out_size, void* d_ws, size_t ws_size,
                              hipStream_t stream) {
    const float* hid  = (const float*)d_in[0];
    const float* Wm   = (const float*)d_in[1];
    const float* bias = (const float*)d_in[2];
    float* out = (float*)d_out;

    const int nrows   = in_sizes[0] / Hdim;   // 16384
    const int nblocks = nrows / RPB;          // 1024

    if (ws_size >= (size_t)(3 * PLANE * sizeof(unsigned short))) {
        convert_w3<<<PLANE / 256, 256, 0, stream>>>(Wm, (unsigned short*)d_ws);
        router_mfma<true><<<nblocks, 256, 0, stream>>>(hid, d_ws, bias, out, nrows);
    } else {
        router_mfma<false><<<nblocks, 256, 0, stream>>>(hid, Wm, bias, out, nrows);
    }
}